// Round 9
// baseline (117.188 us; speedup 1.0000x reference)
//
#include <hip/hip_runtime.h>
#include <hip/hip_fp16.h>
#include <math.h>

#define NBATCH 16
#define CH     32      // CHUNK
#define NP     20      // NPOINTS
#define LPTS   640     // CHUNK * NPOINTS
#define NT     320     // threads per block (5 waves); each thread owns 2 points
#define DIMO   1024
#define TAB    2048    // LDS hash table slots (load factor 0.31)

// Full-wave (64-lane) sum via DPP on the VALU pipe; result valid in lane 63 only.
__device__ __forceinline__ float wave_sum63(float v) {
    v += __int_as_float(__builtin_amdgcn_update_dpp(0, __float_as_int(v), 0x111, 0xF, 0xF, true)); // row_shr:1
    v += __int_as_float(__builtin_amdgcn_update_dpp(0, __float_as_int(v), 0x112, 0xF, 0xF, true)); // row_shr:2
    v += __int_as_float(__builtin_amdgcn_update_dpp(0, __float_as_int(v), 0x114, 0xF, 0xF, true)); // row_shr:4
    v += __int_as_float(__builtin_amdgcn_update_dpp(0, __float_as_int(v), 0x118, 0xF, 0xF, true)); // row_shr:8
    v += __int_as_float(__builtin_amdgcn_update_dpp(0, __float_as_int(v), 0x142, 0xA, 0xF, true)); // row_bcast:15 -> rows 1,3
    v += __int_as_float(__builtin_amdgcn_update_dpp(0, __float_as_int(v), 0x143, 0xC, 0xF, true)); // row_bcast:31 -> rows 2,3
    return v;
}

__global__ __launch_bounds__(NT, 8) void hyper_kernel(
    const float* __restrict__ input,     // (B, 1024)
    const float* __restrict__ res,       // (B, 4096, 4)
    const float* __restrict__ bias,      // (1024)
    const float* __restrict__ u_global,  // (B, 128, 32, 8, 2)
    const float* __restrict__ u_rel,     // (B, 128, 32, 8, 2)
    float* __restrict__ out)             // (B, 1024), zeroed by memset
{
    __shared__ float4 cpar[CH];          // (isig, isig*m0, isig*m1, t3)
    __shared__ float cm0[CH], cm1[CH], cval[CH], colsum[CH];
    __shared__ __align__(16) float cscale[CH];
    // packed dedup table: (h << 11) | flat_point_idx ; EMPTY = ~0ULL
    __shared__ unsigned long long tab[TAB];
    float* const outacc = reinterpret_cast<float*>(tab);  // alias (tab dead after hash)

    const int bk  = blockIdx.x;     // b*128 + k
    const int b   = bk >> 7;
    const int kk  = bk & 127;
    const int tid = threadIdx.x;
    const int c0  = tid / NP;
    const int p   = tid - c0 * NP;
    const int c1  = c0 + 16;        // second point: flat index tid + NT

    const unsigned long long EMPTY = ~0ULL;

    // --- init hash table + per-chunk params --------------------------------
    for (int i = tid; i < TAB; i += NT) tab[i] = EMPTY;

    if (tid < CH) {
        colsum[tid] = 0.0f;
        const float* rp = res + (size_t)(bk * CH + tid) * 4;
        const float r0 = rp[0], r1 = rp[1], r2 = rp[2], r3 = rp[3];
        const float m0 = (1.0f / (1.0f + expf(-r0))) * 1023.0f;
        const float m1 = (1.0f / (1.0f + expf(-r1))) * 1023.0f;
        const float xx = r2 + 2.0f;
        const float sp = fmaxf(xx, 0.0f) + log1pf(expf(-fabsf(xx)));   // softplus
        const float sig = (sp + 1e-6f) * 1024.0f;
        const float isig = 1.0f / (1e-6f + sig);
        cm0[tid] = m0; cm1[tid] = m1;
        cpar[tid] = make_float4(isig, isig * m0, isig * m1, isig * (m0 * m0 + m1 * m1));
        cval[tid] = r3;
    }
    __syncthreads();

    // --- build both points --------------------------------------------------
    const float CEPS = (float)(1.0 - 1e-6);
    int x0, y0, x1, y1;
    {
        const float2* ug = reinterpret_cast<const float2*>(u_global);
        const float2* ur = reinterpret_cast<const float2*>(u_rel);
        #pragma unroll
        for (int q = 0; q < 2; ++q) {
            const int c = q ? c1 : c0;
            const float m0 = cm0[c], m1 = cm1[c];
            int x, y;
            if (p < 4) {
                x = (int)((p & 2) ? ceilf(m0) : floorf(m0));
                y = (int)((p & 1) ? ceilf(m1) : floorf(m1));
            } else if (p < 12) {
                const float2 u = ug[(bk * CH + c) * 8 + (p - 4)];
                x = (int)floorf((u.x * CEPS) * 1024.0f);
                y = (int)floorf((u.y * CEPS) * 1024.0f);
            } else {
                const float2 u = ur[(bk * CH + c) * 8 + (p - 12)];
                const float mn0 = rintf(m0), mn1 = rintf(m1);
                float lo0 = mn0 - 4.0f; if (lo0 < 0.0f) lo0 = 0.0f; if (mn0 + 4.0f > 1024.0f) lo0 = 1016.0f;
                float lo1 = mn1 - 4.0f; if (lo1 < 0.0f) lo1 = 0.0f; if (mn1 + 4.0f > 1024.0f) lo1 = 1016.0f;
                x = (int)floorf((u.x * CEPS) * 8.0f + lo0);
                y = (int)floorf((u.y * CEPS) * 8.0f + lo1);
            }
            if (q) { x1 = x; y1 = y; } else { x0 = x; y0 = y; }
        }
    }

    // hoist input gathers (overlap global latency with hash + pass1)
    const float in0 = input[b * DIMO + y0];
    const float in1 = input[b * DIMO + y1];

    // --- duplicate detection: packed (h<<11 | idx), CAS-claim + atomicMin ---
    int idxA, idxB;
    {
        const unsigned int a0 = (unsigned int)((x0 + 1) * (x0 + 1));              // <= 1025^2
        const unsigned int b3_0 = (unsigned int)((y0 + 1) * (y0 + 1) * (y0 + 1)); // <= 1025^3 < 2^31
        const unsigned long long h0 = (unsigned long long)a0 * b3_0;              // < 2^51
        const unsigned int a1 = (unsigned int)((x1 + 1) * (x1 + 1));
        const unsigned int b3_1 = (unsigned int)((y1 + 1) * (y1 + 1) * (y1 + 1));
        const unsigned long long h1 = (unsigned long long)a1 * b3_1;

        const unsigned long long pk0 = (h0 << 11) | (unsigned long long)tid;
        const unsigned long long pk1 = (h1 << 11) | (unsigned long long)(tid + NT);

        unsigned int hhA = (unsigned int)(h0 ^ (h0 >> 31)) * 2654435761u;
        idxA = (int)(hhA >> 21);
        for (;;) {
            unsigned long long prev = atomicCAS(&tab[idxA], EMPTY, pk0);
            if (prev == EMPTY) break;                       // claimed with our idx
            if ((prev >> 11) == h0) { atomicMin(&tab[idxA], pk0); break; }
            idxA = (idxA + 1) & (TAB - 1);
        }

        unsigned int hhB = (unsigned int)(h1 ^ (h1 >> 31)) * 2654435761u;
        idxB = (int)(hhB >> 21);
        for (;;) {
            unsigned long long prev = atomicCAS(&tab[idxB], EMPTY, pk1);
            if (prev == EMPTY) break;
            if ((prev >> 11) == h1) { atomicMin(&tab[idxB], pk1); break; }
            idxB = (idxB + 1) & (TAB - 1);
        }
    }
    __syncthreads();
    const float keep0 = ((int)(tab[idxA] & 0x7FF) == tid)      ? 1.0f : 0.0f;
    const float keep1 = ((int)(tab[idxB] & 0x7FF) == tid + NT) ? 1.0f : 0.0f;
    __syncthreads();   // everyone done reading tab before outacc overwrites it

    // tab is dead now: reuse as outacc; fold bias in for k==0 block
    for (int i = tid; i < DIMO; i += NT) outacc[i] = (kk == 0) ? bias[i] : 0.0f;

    // --- pass 1: Gaussian props -> column sums; cache props as fp16 ---------
    const float px0 = (float)x0, py0 = (float)y0;
    const float px1 = (float)x1, py1 = (float)y1;
    const float p20 = px0 * px0 + py0 * py0;
    const float p21 = px1 * px1 + py1 * py1;
    const bool lane63 = (tid & 63) == 63;

    __half2 pc0[CH / 2], pc1[CH / 2];
    #pragma unroll
    for (int j = 0; j < CH / 2; ++j) {
        const float4 cpA = cpar[2 * j];
        const float4 cpB = cpar[2 * j + 1];
        const float vA0 = __expf(-0.5f * (cpA.x * p20 - 2.0f * (px0 * cpA.y + py0 * cpA.z) + cpA.w)) * keep0;
        const float vB0 = __expf(-0.5f * (cpB.x * p20 - 2.0f * (px0 * cpB.y + py0 * cpB.z) + cpB.w)) * keep0;
        const float vA1 = __expf(-0.5f * (cpA.x * p21 - 2.0f * (px1 * cpA.y + py1 * cpA.z) + cpA.w)) * keep1;
        const float vB1 = __expf(-0.5f * (cpB.x * p21 - 2.0f * (px1 * cpB.y + py1 * cpB.z) + cpB.w)) * keep1;
        pc0[j] = __floats2half2_rn(vA0, vB0);
        pc1[j] = __floats2half2_rn(vA1, vB1);
        const float sA = wave_sum63(vA0 + vA1);
        const float sB = wave_sum63(vB0 + vB1);
        if (lane63) {
            atomicAdd(&colsum[2 * j], sA);
            atomicAdd(&colsum[2 * j + 1], sB);
        }
    }
    __syncthreads();
    if (tid < CH) cscale[tid] = cval[tid] / colsum[tid];
    __syncthreads();

    // --- pass 2: weighted sums from fp16 cache ------------------------------
    float val0 = 0.0f, val1 = 0.0f;
    const float4* cs4 = reinterpret_cast<const float4*>(cscale);
    #pragma unroll
    for (int i = 0; i < CH / 4; ++i) {
        const float4 sc = cs4[i];
        const float2 a0 = __half22float2(pc0[2 * i]);
        const float2 b0 = __half22float2(pc0[2 * i + 1]);
        val0 += a0.x * sc.x + a0.y * sc.y + b0.x * sc.z + b0.y * sc.w;
        const float2 a1 = __half22float2(pc1[2 * i]);
        const float2 b1 = __half22float2(pc1[2 * i + 1]);
        val1 += a1.x * sc.x + a1.y * sc.y + b1.x * sc.z + b1.y * sc.w;
    }

    // --- stage scatter in LDS, flush coalesced ------------------------------
    atomicAdd(&outacc[x0], val0 * in0);
    atomicAdd(&outacc[x1], val1 * in1);
    __syncthreads();

    for (int i = tid; i < DIMO; i += NT) {
        const float v = outacc[i];
        if (v != 0.0f) atomicAdd(&out[b * DIMO + i], v);
    }
}

extern "C" void kernel_launch(void* const* d_in, const int* in_sizes, int n_in,
                              void* d_out, int out_size, void* d_ws, size_t ws_size,
                              hipStream_t stream) {
    const float* input  = (const float*)d_in[0];
    const float* res    = (const float*)d_in[1];
    const float* bias   = (const float*)d_in[2];
    const float* u_glob = (const float*)d_in[3];
    const float* u_rel  = (const float*)d_in[4];
    // d_in[5] = temp_indices: dead in the reference (both columns overwritten)
    float* out = (float*)d_out;

    hipMemsetAsync(out, 0, (size_t)NBATCH * DIMO * sizeof(float), stream);
    hipLaunchKernelGGL(hyper_kernel, dim3(NBATCH * 128), dim3(NT), 0, stream,
                       input, res, bias, u_glob, u_rel, out);
}

// Round 10
// 107.960 us; speedup vs baseline: 1.0855x; 1.0855x over previous
//
#include <hip/hip_runtime.h>
#include <math.h>

#define NBATCH 16
#define CH     32      // CHUNK
#define NP     20      // NPOINTS
#define LPTS   640     // CHUNK * NPOINTS
#define NT     320     // threads per block (5 waves); each thread owns 2 points
#define DIMO   1024
#define TAB    2048    // LDS hash table slots (load factor 0.31)

// Full-wave (64-lane) sum via DPP on the VALU pipe; result valid in lane 63 only.
__device__ __forceinline__ float wave_sum63(float v) {
    v += __int_as_float(__builtin_amdgcn_update_dpp(0, __float_as_int(v), 0x111, 0xF, 0xF, true)); // row_shr:1
    v += __int_as_float(__builtin_amdgcn_update_dpp(0, __float_as_int(v), 0x112, 0xF, 0xF, true)); // row_shr:2
    v += __int_as_float(__builtin_amdgcn_update_dpp(0, __float_as_int(v), 0x114, 0xF, 0xF, true)); // row_shr:4
    v += __int_as_float(__builtin_amdgcn_update_dpp(0, __float_as_int(v), 0x118, 0xF, 0xF, true)); // row_shr:8
    v += __int_as_float(__builtin_amdgcn_update_dpp(0, __float_as_int(v), 0x142, 0xA, 0xF, true)); // row_bcast:15 -> rows 1,3
    v += __int_as_float(__builtin_amdgcn_update_dpp(0, __float_as_int(v), 0x143, 0xC, 0xF, true)); // row_bcast:31 -> rows 2,3
    return v;
}

__global__ __launch_bounds__(NT, 8) void hyper_kernel(
    const float* __restrict__ input,     // (B, 1024)
    const float* __restrict__ res,       // (B, 4096, 4)
    const float* __restrict__ bias,      // (1024)
    const float* __restrict__ u_global,  // (B, 128, 32, 8, 2)
    const float* __restrict__ u_rel,     // (B, 128, 32, 8, 2)
    float* __restrict__ out)             // (B, 1024), zeroed by memset
{
    // cpar[c] = (A,B,C,D): prop = exp2(A*p2 + B*px + C*py + D)
    //   A = -0.5*L2E*isig, B = L2E*isig*m0, C = L2E*isig*m1, D = -0.5*L2E*isig*(m0^2+m1^2)
    __shared__ float4 cpar[CH];
    __shared__ float cm0[CH], cm1[CH], cval[CH], colsum[CH];
    __shared__ __align__(16) float cscale[CH];
    // packed dedup table: (h << 11) | flat_point_idx ; EMPTY = ~0ULL
    __shared__ unsigned long long tab[TAB];
    float* const outacc = reinterpret_cast<float*>(tab);  // alias (tab dead after hash)

    const int bk  = blockIdx.x;     // b*128 + k
    const int b   = bk >> 7;
    const int kk  = bk & 127;
    const int tid = threadIdx.x;
    const int c0  = tid / NP;
    const int p   = tid - c0 * NP;
    const int c1  = c0 + 16;        // second point: flat index tid + NT

    const unsigned long long EMPTY = ~0ULL;
    const float L2E = 1.4426950408889634f;

    // --- init hash table + per-chunk params --------------------------------
    for (int i = tid; i < TAB; i += NT) tab[i] = EMPTY;

    if (tid < CH) {
        colsum[tid] = 0.0f;
        const float* rp = res + (size_t)(bk * CH + tid) * 4;
        const float r0 = rp[0], r1 = rp[1], r2 = rp[2], r3 = rp[3];
        const float m0 = (1.0f / (1.0f + expf(-r0))) * 1023.0f;
        const float m1 = (1.0f / (1.0f + expf(-r1))) * 1023.0f;
        const float xx = r2 + 2.0f;
        const float sp = fmaxf(xx, 0.0f) + log1pf(expf(-fabsf(xx)));   // softplus
        const float sig = (sp + 1e-6f) * 1024.0f;
        const float isig = 1.0f / (1e-6f + sig);
        cm0[tid] = m0; cm1[tid] = m1;
        const float hA = -0.5f * L2E * isig;
        cpar[tid] = make_float4(hA, L2E * isig * m0, L2E * isig * m1,
                                hA * (m0 * m0 + m1 * m1));
        cval[tid] = r3;
    }
    __syncthreads();

    // --- build both points --------------------------------------------------
    const float CEPS = (float)(1.0 - 1e-6);
    int x0, y0, x1, y1;
    {
        const float2* ug = reinterpret_cast<const float2*>(u_global);
        const float2* ur = reinterpret_cast<const float2*>(u_rel);
        #pragma unroll
        for (int q = 0; q < 2; ++q) {
            const int c = q ? c1 : c0;
            const float m0 = cm0[c], m1 = cm1[c];
            int x, y;
            if (p < 4) {
                x = (int)((p & 2) ? ceilf(m0) : floorf(m0));
                y = (int)((p & 1) ? ceilf(m1) : floorf(m1));
            } else if (p < 12) {
                const float2 u = ug[(bk * CH + c) * 8 + (p - 4)];
                x = (int)floorf((u.x * CEPS) * 1024.0f);
                y = (int)floorf((u.y * CEPS) * 1024.0f);
            } else {
                const float2 u = ur[(bk * CH + c) * 8 + (p - 12)];
                const float mn0 = rintf(m0), mn1 = rintf(m1);
                float lo0 = mn0 - 4.0f; if (lo0 < 0.0f) lo0 = 0.0f; if (mn0 + 4.0f > 1024.0f) lo0 = 1016.0f;
                float lo1 = mn1 - 4.0f; if (lo1 < 0.0f) lo1 = 0.0f; if (mn1 + 4.0f > 1024.0f) lo1 = 1016.0f;
                x = (int)floorf((u.x * CEPS) * 8.0f + lo0);
                y = (int)floorf((u.y * CEPS) * 8.0f + lo1);
            }
            if (q) { x1 = x; y1 = y; } else { x0 = x; y0 = y; }
        }
    }

    // hoist input gathers (overlap global latency with hash + pass1)
    const float in0 = input[b * DIMO + y0];
    const float in1 = input[b * DIMO + y1];

    // --- duplicate detection: packed (h<<11 | idx), CAS-claim + atomicMin ---
    int idxA, idxB;
    {
        const unsigned int a0 = (unsigned int)((x0 + 1) * (x0 + 1));              // <= 1025^2
        const unsigned int b3_0 = (unsigned int)((y0 + 1) * (y0 + 1) * (y0 + 1)); // <= 1025^3 < 2^31
        const unsigned long long h0 = (unsigned long long)a0 * b3_0;              // < 2^51
        const unsigned int a1 = (unsigned int)((x1 + 1) * (x1 + 1));
        const unsigned int b3_1 = (unsigned int)((y1 + 1) * (y1 + 1) * (y1 + 1));
        const unsigned long long h1 = (unsigned long long)a1 * b3_1;

        const unsigned long long pk0 = (h0 << 11) | (unsigned long long)tid;
        const unsigned long long pk1 = (h1 << 11) | (unsigned long long)(tid + NT);

        unsigned int hhA = (unsigned int)(h0 ^ (h0 >> 31)) * 2654435761u;
        idxA = (int)(hhA >> 21);
        for (;;) {
            unsigned long long prev = atomicCAS(&tab[idxA], EMPTY, pk0);
            if (prev == EMPTY) break;                       // claimed with our idx
            if ((prev >> 11) == h0) { atomicMin(&tab[idxA], pk0); break; }
            idxA = (idxA + 1) & (TAB - 1);
        }

        unsigned int hhB = (unsigned int)(h1 ^ (h1 >> 31)) * 2654435761u;
        idxB = (int)(hhB >> 21);
        for (;;) {
            unsigned long long prev = atomicCAS(&tab[idxB], EMPTY, pk1);
            if (prev == EMPTY) break;
            if ((prev >> 11) == h1) { atomicMin(&tab[idxB], pk1); break; }
            idxB = (idxB + 1) & (TAB - 1);
        }
    }
    __syncthreads();
    const float keep0 = ((int)(tab[idxA] & 0x7FF) == tid)      ? 1.0f : 0.0f;
    const float keep1 = ((int)(tab[idxB] & 0x7FF) == tid + NT) ? 1.0f : 0.0f;
    __syncthreads();   // everyone done reading tab before outacc overwrites it

    // tab is dead now: reuse as outacc; fold bias in for k==0 block
    for (int i = tid; i < DIMO; i += NT) outacc[i] = (kk == 0) ? bias[i] : 0.0f;

    // --- pass 1: Gaussian props -> column sums (recompute in pass 2) --------
    const float px0 = (float)x0, py0 = (float)y0;
    const float px1 = (float)x1, py1 = (float)y1;
    const float p20 = px0 * px0 + py0 * py0;
    const float p21 = px1 * px1 + py1 * py1;
    const bool lane63 = (tid & 63) == 63;

    #pragma unroll
    for (int j = 0; j < CH / 2; ++j) {
        const float4 cpA = cpar[2 * j];
        const float4 cpB = cpar[2 * j + 1];
        const float vA0 = __builtin_amdgcn_exp2f(fmaf(cpA.x, p20, fmaf(cpA.y, px0, fmaf(cpA.z, py0, cpA.w)))) * keep0;
        const float vB0 = __builtin_amdgcn_exp2f(fmaf(cpB.x, p20, fmaf(cpB.y, px0, fmaf(cpB.z, py0, cpB.w)))) * keep0;
        const float vA1 = __builtin_amdgcn_exp2f(fmaf(cpA.x, p21, fmaf(cpA.y, px1, fmaf(cpA.z, py1, cpA.w)))) * keep1;
        const float vB1 = __builtin_amdgcn_exp2f(fmaf(cpB.x, p21, fmaf(cpB.y, px1, fmaf(cpB.z, py1, cpB.w)))) * keep1;
        const float sA = wave_sum63(vA0 + vA1);
        const float sB = wave_sum63(vB0 + vB1);
        if (lane63) {
            atomicAdd(&colsum[2 * j], sA);
            atomicAdd(&colsum[2 * j + 1], sB);
        }
    }
    __syncthreads();
    if (tid < CH) cscale[tid] = cval[tid] / colsum[tid];
    __syncthreads();

    // --- pass 2: recompute props, weighted sums (exact f32) -----------------
    float val0 = 0.0f, val1 = 0.0f;
    #pragma unroll
    for (int cc = 0; cc < CH; ++cc) {
        const float4 cp = cpar[cc];
        const float sc = cscale[cc];
        val0 = fmaf(__builtin_amdgcn_exp2f(fmaf(cp.x, p20, fmaf(cp.y, px0, fmaf(cp.z, py0, cp.w)))), sc, val0);
        val1 = fmaf(__builtin_amdgcn_exp2f(fmaf(cp.x, p21, fmaf(cp.y, px1, fmaf(cp.z, py1, cp.w)))), sc, val1);
    }
    val0 *= keep0;
    val1 *= keep1;

    // --- stage scatter in LDS, flush coalesced ------------------------------
    atomicAdd(&outacc[x0], val0 * in0);
    atomicAdd(&outacc[x1], val1 * in1);
    __syncthreads();

    for (int i = tid; i < DIMO; i += NT) {
        const float v = outacc[i];
        if (v != 0.0f) atomicAdd(&out[b * DIMO + i], v);
    }
}

extern "C" void kernel_launch(void* const* d_in, const int* in_sizes, int n_in,
                              void* d_out, int out_size, void* d_ws, size_t ws_size,
                              hipStream_t stream) {
    const float* input  = (const float*)d_in[0];
    const float* res    = (const float*)d_in[1];
    const float* bias   = (const float*)d_in[2];
    const float* u_glob = (const float*)d_in[3];
    const float* u_rel  = (const float*)d_in[4];
    // d_in[5] = temp_indices: dead in the reference (both columns overwritten)
    float* out = (float*)d_out;

    hipMemsetAsync(out, 0, (size_t)NBATCH * DIMO * sizeof(float), stream);
    hipLaunchKernelGGL(hyper_kernel, dim3(NBATCH * 128), dim3(NT), 0, stream,
                       input, res, bias, u_glob, u_rel, out);
}

// Round 11
// 107.099 us; speedup vs baseline: 1.0942x; 1.0080x over previous
//
#include <hip/hip_runtime.h>
#include <math.h>

#define NBATCH 16
#define CH     32      // CHUNK
#define NP     20      // NPOINTS
#define LPTS   640     // CHUNK * NPOINTS
#define NT     320     // threads per block (5 waves); each thread owns 2 points
#define DIMO   1024
#define TAB    2048    // LDS hash table slots (load factor 0.31)
#define GRID   1024    // 4 blocks/CU exactly; each block does 2 rows sequentially

// Full-wave (64-lane) sum via DPP on the VALU pipe; result valid in lane 63 only.
__device__ __forceinline__ float wave_sum63(float v) {
    v += __int_as_float(__builtin_amdgcn_update_dpp(0, __float_as_int(v), 0x111, 0xF, 0xF, true)); // row_shr:1
    v += __int_as_float(__builtin_amdgcn_update_dpp(0, __float_as_int(v), 0x112, 0xF, 0xF, true)); // row_shr:2
    v += __int_as_float(__builtin_amdgcn_update_dpp(0, __float_as_int(v), 0x114, 0xF, 0xF, true)); // row_shr:4
    v += __int_as_float(__builtin_amdgcn_update_dpp(0, __float_as_int(v), 0x118, 0xF, 0xF, true)); // row_shr:8
    v += __int_as_float(__builtin_amdgcn_update_dpp(0, __float_as_int(v), 0x142, 0xA, 0xF, true)); // row_bcast:15 -> rows 1,3
    v += __int_as_float(__builtin_amdgcn_update_dpp(0, __float_as_int(v), 0x143, 0xC, 0xF, true)); // row_bcast:31 -> rows 2,3
    return v;
}

__global__ __launch_bounds__(NT, 8) void hyper_kernel(
    const float* __restrict__ input,     // (B, 1024)
    const float* __restrict__ res,       // (B, 4096, 4)
    const float* __restrict__ bias,      // (1024)
    const float* __restrict__ u_global,  // (B, 128, 32, 8, 2)
    const float* __restrict__ u_rel,     // (B, 128, 32, 8, 2)
    float* __restrict__ out)             // (B, 1024), zeroed by memset
{
    // cpar[c] = (A,B,C,D): prop = exp2(A*p2 + B*px + C*py + D)
    __shared__ float4 cpar[CH];
    __shared__ float cm0[CH], cm1[CH], cval[CH], colsum[CH];
    __shared__ __align__(16) float cscale[CH];
    // packed dedup table: (h << 11) | flat_point_idx ; EMPTY = ~0ULL
    __shared__ unsigned long long tab[TAB];
    float* const outacc = reinterpret_cast<float*>(tab);  // alias (tab dead after hash)

    const int tid = threadIdx.x;
    const int c0  = tid / NP;
    const int p   = tid - c0 * NP;
    const int c1  = c0 + 16;        // second point: flat index tid + NT

    const unsigned long long EMPTY = ~0ULL;
    const float L2E = 1.4426950408889634f;
    const float CEPS = (float)(1.0 - 1e-6);

    for (int rep = 0; rep < 2; ++rep) {
        const int bk  = blockIdx.x + rep * GRID;   // b*128 + k
        const int b   = bk >> 7;
        const int kk  = bk & 127;

        // --- init hash table + per-chunk params ----------------------------
        for (int i = tid; i < TAB; i += NT) tab[i] = EMPTY;

        if (tid < CH) {
            colsum[tid] = 0.0f;
            const float* rp = res + (size_t)(bk * CH + tid) * 4;
            const float r0 = rp[0], r1 = rp[1], r2 = rp[2], r3 = rp[3];
            const float m0 = (1.0f / (1.0f + expf(-r0))) * 1023.0f;
            const float m1 = (1.0f / (1.0f + expf(-r1))) * 1023.0f;
            const float xx = r2 + 2.0f;
            const float sp = fmaxf(xx, 0.0f) + log1pf(expf(-fabsf(xx)));   // softplus
            const float sig = (sp + 1e-6f) * 1024.0f;
            const float isig = 1.0f / (1e-6f + sig);
            cm0[tid] = m0; cm1[tid] = m1;
            const float hA = -0.5f * L2E * isig;
            cpar[tid] = make_float4(hA, L2E * isig * m0, L2E * isig * m1,
                                    hA * (m0 * m0 + m1 * m1));
            cval[tid] = r3;
        }
        __syncthreads();

        // --- build both points ---------------------------------------------
        int x0, y0, x1, y1;
        {
            const float2* ug = reinterpret_cast<const float2*>(u_global);
            const float2* ur = reinterpret_cast<const float2*>(u_rel);
            #pragma unroll
            for (int q = 0; q < 2; ++q) {
                const int c = q ? c1 : c0;
                const float m0 = cm0[c], m1 = cm1[c];
                int x, y;
                if (p < 4) {
                    x = (int)((p & 2) ? ceilf(m0) : floorf(m0));
                    y = (int)((p & 1) ? ceilf(m1) : floorf(m1));
                } else if (p < 12) {
                    const float2 u = ug[(bk * CH + c) * 8 + (p - 4)];
                    x = (int)floorf((u.x * CEPS) * 1024.0f);
                    y = (int)floorf((u.y * CEPS) * 1024.0f);
                } else {
                    const float2 u = ur[(bk * CH + c) * 8 + (p - 12)];
                    const float mn0 = rintf(m0), mn1 = rintf(m1);
                    float lo0 = mn0 - 4.0f; if (lo0 < 0.0f) lo0 = 0.0f; if (mn0 + 4.0f > 1024.0f) lo0 = 1016.0f;
                    float lo1 = mn1 - 4.0f; if (lo1 < 0.0f) lo1 = 0.0f; if (mn1 + 4.0f > 1024.0f) lo1 = 1016.0f;
                    x = (int)floorf((u.x * CEPS) * 8.0f + lo0);
                    y = (int)floorf((u.y * CEPS) * 8.0f + lo1);
                }
                if (q) { x1 = x; y1 = y; } else { x0 = x; y0 = y; }
            }
        }

        // hoist input gathers (overlap global latency with hash + pass1)
        const float in0 = input[b * DIMO + y0];
        const float in1 = input[b * DIMO + y1];

        // --- duplicate detection: packed (h<<11 | idx), CAS-claim + atomicMin
        int idxA, idxB;
        {
            const unsigned int a0 = (unsigned int)((x0 + 1) * (x0 + 1));              // <= 1025^2
            const unsigned int b3_0 = (unsigned int)((y0 + 1) * (y0 + 1) * (y0 + 1)); // <= 1025^3 < 2^31
            const unsigned long long h0 = (unsigned long long)a0 * b3_0;              // < 2^51
            const unsigned int a1 = (unsigned int)((x1 + 1) * (x1 + 1));
            const unsigned int b3_1 = (unsigned int)((y1 + 1) * (y1 + 1) * (y1 + 1));
            const unsigned long long h1 = (unsigned long long)a1 * b3_1;

            const unsigned long long pk0 = (h0 << 11) | (unsigned long long)tid;
            const unsigned long long pk1 = (h1 << 11) | (unsigned long long)(tid + NT);

            unsigned int hhA = (unsigned int)(h0 ^ (h0 >> 31)) * 2654435761u;
            idxA = (int)(hhA >> 21);
            for (;;) {
                unsigned long long prev = atomicCAS(&tab[idxA], EMPTY, pk0);
                if (prev == EMPTY) break;                       // claimed with our idx
                if ((prev >> 11) == h0) { atomicMin(&tab[idxA], pk0); break; }
                idxA = (idxA + 1) & (TAB - 1);
            }

            unsigned int hhB = (unsigned int)(h1 ^ (h1 >> 31)) * 2654435761u;
            idxB = (int)(hhB >> 21);
            for (;;) {
                unsigned long long prev = atomicCAS(&tab[idxB], EMPTY, pk1);
                if (prev == EMPTY) break;
                if ((prev >> 11) == h1) { atomicMin(&tab[idxB], pk1); break; }
                idxB = (idxB + 1) & (TAB - 1);
            }
        }
        __syncthreads();
        const float keep0 = ((int)(tab[idxA] & 0x7FF) == tid)      ? 1.0f : 0.0f;
        const float keep1 = ((int)(tab[idxB] & 0x7FF) == tid + NT) ? 1.0f : 0.0f;
        __syncthreads();   // everyone done reading tab before outacc overwrites it

        // tab is dead now: reuse as outacc; fold bias in for k==0 block
        for (int i = tid; i < DIMO; i += NT) outacc[i] = (kk == 0) ? bias[i] : 0.0f;

        // --- pass 1: Gaussian props -> column sums (recompute in pass 2) ----
        const float px0 = (float)x0, py0 = (float)y0;
        const float px1 = (float)x1, py1 = (float)y1;
        const float p20 = px0 * px0 + py0 * py0;
        const float p21 = px1 * px1 + py1 * py1;
        const bool lane63 = (tid & 63) == 63;

        #pragma unroll
        for (int j = 0; j < CH / 2; ++j) {
            const float4 cpA = cpar[2 * j];
            const float4 cpB = cpar[2 * j + 1];
            const float vA0 = __builtin_amdgcn_exp2f(fmaf(cpA.x, p20, fmaf(cpA.y, px0, fmaf(cpA.z, py0, cpA.w)))) * keep0;
            const float vB0 = __builtin_amdgcn_exp2f(fmaf(cpB.x, p20, fmaf(cpB.y, px0, fmaf(cpB.z, py0, cpB.w)))) * keep0;
            const float vA1 = __builtin_amdgcn_exp2f(fmaf(cpA.x, p21, fmaf(cpA.y, px1, fmaf(cpA.z, py1, cpA.w)))) * keep1;
            const float vB1 = __builtin_amdgcn_exp2f(fmaf(cpB.x, p21, fmaf(cpB.y, px1, fmaf(cpB.z, py1, cpB.w)))) * keep1;
            const float sA = wave_sum63(vA0 + vA1);
            const float sB = wave_sum63(vB0 + vB1);
            if (lane63) {
                atomicAdd(&colsum[2 * j], sA);
                atomicAdd(&colsum[2 * j + 1], sB);
            }
        }
        __syncthreads();
        if (tid < CH) cscale[tid] = cval[tid] / colsum[tid];
        __syncthreads();

        // --- pass 2: recompute props, weighted sums (exact f32) -------------
        float val0 = 0.0f, val1 = 0.0f;
        #pragma unroll
        for (int cc = 0; cc < CH; ++cc) {
            const float4 cp = cpar[cc];
            const float sc = cscale[cc];
            val0 = fmaf(__builtin_amdgcn_exp2f(fmaf(cp.x, p20, fmaf(cp.y, px0, fmaf(cp.z, py0, cp.w)))), sc, val0);
            val1 = fmaf(__builtin_amdgcn_exp2f(fmaf(cp.x, p21, fmaf(cp.y, px1, fmaf(cp.z, py1, cp.w)))), sc, val1);
        }
        val0 *= keep0;
        val1 *= keep1;

        // --- stage scatter in LDS, flush coalesced --------------------------
        atomicAdd(&outacc[x0], val0 * in0);
        atomicAdd(&outacc[x1], val1 * in1);
        __syncthreads();

        for (int i = tid; i < DIMO; i += NT) {
            const float v = outacc[i];
            if (v != 0.0f) atomicAdd(&out[b * DIMO + i], v);
        }
        __syncthreads();   // all flush reads done before next rep re-inits tab
    }
}

extern "C" void kernel_launch(void* const* d_in, const int* in_sizes, int n_in,
                              void* d_out, int out_size, void* d_ws, size_t ws_size,
                              hipStream_t stream) {
    const float* input  = (const float*)d_in[0];
    const float* res    = (const float*)d_in[1];
    const float* bias   = (const float*)d_in[2];
    const float* u_glob = (const float*)d_in[3];
    const float* u_rel  = (const float*)d_in[4];
    // d_in[5] = temp_indices: dead in the reference (both columns overwritten)
    float* out = (float*)d_out;

    hipMemsetAsync(out, 0, (size_t)NBATCH * DIMO * sizeof(float), stream);
    hipLaunchKernelGGL(hyper_kernel, dim3(GRID), dim3(NT), 0, stream,
                       input, res, bias, u_glob, u_rel, out);
}